// Round 1
// baseline (40767.084 us; speedup 1.0000x reference)
//
#include <hip/hip_runtime.h>
#include <hip/hip_bf16.h>

#define TT 512
#define BB 256
#define INS 128
#define HH 256
#define SP1 129
#define NBLK 256
#define BT 16
#define HT 16

__device__ __forceinline__ float sigmoidf_(float v) { return 1.0f / (1.0f + expf(-v)); }

// pts[t][b] = cumsum of ops[0..t][b]  (ops[0]==0)
__global__ void k_pts(const int* __restrict__ ops, int* __restrict__ pts) {
    int b = threadIdx.x;
    int acc = 0;
    for (int t = 0; t < TT; ++t) {
        acc += ops[t * BB + b];
        pts[t * BB + b] = acc;
    }
}

// level 0 of the stacks = h0/c0 broadcast over batch
__global__ void k_init(const float* __restrict__ h0, const float* __restrict__ c0,
                       float* __restrict__ hS, float* __restrict__ cS) {
    int i = blockIdx.x * 256 + threadIdx.x;   // i = b*HH + h, level 0
    int h = i & (HH - 1);
    hS[i] = h0[h];
    cS[i] = c0[h];
}

// device-scope grid barrier: bar[0]=arrival counter, bar[1]=release generation
__device__ __forceinline__ void grid_barrier(unsigned* bar, unsigned gen) {
    __syncthreads();
    if (threadIdx.x == 0) {
        __threadfence();  // release: write back this block's stores (device scope)
        unsigned prev = __hip_atomic_fetch_add(&bar[0], 1u, __ATOMIC_ACQ_REL,
                                               __HIP_MEMORY_SCOPE_AGENT);
        if (prev == NBLK - 1u) {
            __hip_atomic_store(&bar[0], 0u, __ATOMIC_RELAXED, __HIP_MEMORY_SCOPE_AGENT);
            __hip_atomic_store(&bar[1], gen, __ATOMIC_RELEASE, __HIP_MEMORY_SCOPE_AGENT);
        } else {
            while (__hip_atomic_load(&bar[1], __ATOMIC_RELAXED,
                                     __HIP_MEMORY_SCOPE_AGENT) < gen) {
                __builtin_amdgcn_s_sleep(2);
            }
        }
        __threadfence();  // acquire: invalidate stale L1/L2 before next step's gathers
    }
    __syncthreads();
}

__global__ __launch_bounds__(256)
void k_main(const float* __restrict__ x, const int* __restrict__ ops,
            const float* __restrict__ wxi, const float* __restrict__ bi,
            const float* __restrict__ whi, const float* __restrict__ wci,
            const float* __restrict__ wxf, const float* __restrict__ bfp,
            const float* __restrict__ whf, const float* __restrict__ wcf,
            const float* __restrict__ wxc, const float* __restrict__ bcp,
            const float* __restrict__ wxo, const float* __restrict__ bop,
            const float* __restrict__ who, const float* __restrict__ wco,
            float* __restrict__ hS, float* __restrict__ cS,
            const int* __restrict__ pts, unsigned* __restrict__ bar,
            float* __restrict__ out)
{
    const int tid   = threadIdx.x;
    const int blk   = blockIdx.x;
    const int btile = blk & 15;    // 16 batch-tiles of 16
    const int htile = blk >> 4;    // 16 h-tiles of 16
    const int hl = tid & 15, bl = tid >> 4;
    const int hg = htile * HT + hl;
    const int bg = btile * BT + bl;

    // +4 pad keeps float4 alignment AND offsets rows by 4 banks (conflict-free reads)
    __shared__ float sh[BT][HH + 4];
    __shared__ float sc[BT][HH + 4];

    const float bi_ = bi[hg], bf_ = bfp[hg], bc_ = bcp[hg], bo_ = bop[hg];
    const float* wxi_r = wxi + hg * INS;
    const float* wxf_r = wxf + hg * INS;
    const float* wxc_r = wxc + hg * INS;
    const float* wxo_r = wxo + hg * INS;
    const float* whi_r = whi + hg * HH;
    const float* whf_r = whf + hg * HH;
    const float* who_r = who + hg * HH;
    const float* wci_r = wci + hg * HH;
    const float* wcf_r = wcf + hg * HH;
    const float* wco_r = wco + hg * HH;

    for (int t = 0; t < TT; ++t) {
        const int tB = t * BB;

        // ---- stage cur_h / cur_c (gather by per-batch stack pointer) ----
        {
            int r0 = tid >> 6;       // 4 rows per pass (64 float4 per row)
            int c4 = tid & 63;
#pragma unroll
            for (int p = 0; p < 4; ++p) {
                int rr  = p * 4 + r0;
                int bgr = btile * BT + rr;
                int pt  = pts[tB + bgr];
                size_t base = ((size_t)pt * BB + bgr) * HH;
                float4 hv = *(const float4*)(hS + base + c4 * 4);
                float4 cv = *(const float4*)(cS + base + c4 * 4);
                *(float4*)&sh[rr][c4 * 4] = hv;
                *(float4*)&sc[rr][c4 * 4] = cv;
            }
        }
        __syncthreads();

        // ---- per-thread output (bg, hg): 10 dot products ----
        float a_i = bi_, a_o = bo_;
        float a_xf = 0.f, a_hf = 0.f, a_cf = 0.f, a_xc = 0.f;

        const float* xrow = x + ((size_t)tB + bg) * INS;
#pragma unroll 8
        for (int k = 0; k < INS; k += 4) {
            float4 xv = *(const float4*)(xrow + k);
            float4 w;
            w = *(const float4*)(wxi_r + k); a_i  += xv.x*w.x + xv.y*w.y + xv.z*w.z + xv.w*w.w;
            w = *(const float4*)(wxf_r + k); a_xf += xv.x*w.x + xv.y*w.y + xv.z*w.z + xv.w*w.w;
            w = *(const float4*)(wxc_r + k); a_xc += xv.x*w.x + xv.y*w.y + xv.z*w.z + xv.w*w.w;
            w = *(const float4*)(wxo_r + k); a_o  += xv.x*w.x + xv.y*w.y + xv.z*w.z + xv.w*w.w;
        }
#pragma unroll 4
        for (int k = 0; k < HH; k += 4) {
            float4 hv = *(const float4*)&sh[bl][k];
            float4 cv = *(const float4*)&sc[bl][k];
            float4 w;
            w = *(const float4*)(whi_r + k); a_i  += hv.x*w.x + hv.y*w.y + hv.z*w.z + hv.w*w.w;
            w = *(const float4*)(wci_r + k); a_i  += cv.x*w.x + cv.y*w.y + cv.z*w.z + cv.w*w.w;
            w = *(const float4*)(whf_r + k); a_hf += hv.x*w.x + hv.y*w.y + hv.z*w.z + hv.w*w.w;
            w = *(const float4*)(wcf_r + k); a_cf += cv.x*w.x + cv.y*w.y + cv.z*w.z + cv.w*w.w;
            w = *(const float4*)(who_r + k); a_o  += hv.x*w.x + hv.y*w.y + hv.z*w.z + hv.w*w.w;
            w = *(const float4*)(wco_r + k); a_o  += cv.x*w.x + cv.y*w.y + cv.z*w.z + cv.w*w.w;
        }

        float ig = sigmoidf_(a_i);
        float fg = sigmoidf_(a_xf + bf_ + a_hf + a_cf);
        float og = sigmoidf_(a_o);
        float curc = sc[bl][hg];
        float cg = fg * curc + ig * tanhf(a_xc + bc_ + a_hf);  // NOTE: w_hf reuse, per ref
        float nh = og * tanhf(cg);

        int pt = pts[tB + bg];
        int op = ops[(t + 1) * BB + bg];
        size_t wix = ((size_t)(pt + 1) * BB + bg) * HH + hg;
        hS[wix] = nh;
        cS[wix] = cg;

        float ret;
        if (op > 0) {
            ret = nh;
        } else {
            int pm = (pt == 0) ? (SP1 - 1) : (pt - 1);
            ret = hS[((size_t)pm * BB + bg) * HH + hg];
        }
        out[((size_t)tB + bg) * HH + hg] = ret;

        grid_barrier(bar, (unsigned)(t + 1));
    }
}

extern "C" void kernel_launch(void* const* d_in, const int* in_sizes, int n_in,
                              void* d_out, int out_size, void* d_ws, size_t ws_size,
                              hipStream_t stream) {
    const float* x   = (const float*)d_in[0];
    const int*   ops = (const int*)d_in[1];
    const float* wxi = (const float*)d_in[2];
    const float* bi  = (const float*)d_in[3];
    const float* whi = (const float*)d_in[4];
    const float* wci = (const float*)d_in[5];
    const float* wxf = (const float*)d_in[6];
    const float* bf  = (const float*)d_in[7];
    const float* whf = (const float*)d_in[8];
    const float* wcf = (const float*)d_in[9];
    const float* wxc = (const float*)d_in[10];
    const float* bc  = (const float*)d_in[11];
    const float* wxo = (const float*)d_in[12];
    const float* bo  = (const float*)d_in[13];
    const float* who = (const float*)d_in[14];
    const float* wco = (const float*)d_in[15];
    const float* h0  = (const float*)d_in[16];
    const float* c0  = (const float*)d_in[17];
    float* out = (float*)d_out;

    const size_t stackElems = (size_t)SP1 * BB * HH;  // 8,454,144 floats per stack
    float*    hS  = (float*)d_ws;
    float*    cS  = hS + stackElems;
    int*      pts = (int*)(cS + stackElems);
    unsigned* bar = (unsigned*)((char*)pts + (size_t)TT * BB * sizeof(int));
    size_t need = (size_t)((char*)bar + 256 - (char*)d_ws);
    if (ws_size < need) return;  // ws too small; fail loudly via wrong output

    // stacks must start as zeros (level 128 IS read as zeros when pt==0)
    hipMemsetAsync(d_ws, 0, stackElems * 2 * sizeof(float), stream);
    hipMemsetAsync((void*)bar, 0, 256, stream);
    k_pts<<<1, 256, 0, stream>>>(ops, pts);
    k_init<<<(BB * HH) / 256, 256, 0, stream>>>(h0, c0, hS, cS);
    k_main<<<NBLK, 256, 0, stream>>>(x, ops, wxi, bi, whi, wci, wxf, bf, whf, wcf,
                                     wxc, bc, wxo, bo, who, wco,
                                     hS, cS, pts, bar, out);
}

// Round 3
// 33553.601 us; speedup vs baseline: 1.2150x; 1.2150x over previous
//
#include <hip/hip_runtime.h>
#include <hip/hip_bf16.h>

#define TT 512
#define BB 256
#define INS 128
#define HH 256
#define SP1 129
#define NBLK 256
#define BT 16
#define HT 16

__device__ __forceinline__ float sigmoidf_(float v) { return 1.0f / (1.0f + expf(-v)); }

// Cache-bypass (coherence-point) accessors for cross-block data exchange.
// Relaxed system-scope atomics compile to global_load/store with sc0 sc1 on
// gfx950 -> bypass L1/L2, coherent at MALL. No buffer_wbl2/inv needed anywhere.
__device__ __forceinline__ float ld_coh(const float* p) {
    return __hip_atomic_load(p, __ATOMIC_RELAXED, __HIP_MEMORY_SCOPE_SYSTEM);
}
__device__ __forceinline__ void st_coh(float* p, float v) {
    __hip_atomic_store(p, v, __ATOMIC_RELAXED, __HIP_MEMORY_SCOPE_SYSTEM);
}

// pts[t][b] = cumsum of ops[0..t][b]  (ops[0]==0)
__global__ void k_pts(const int* __restrict__ ops, int* __restrict__ pts) {
    int b = threadIdx.x;
    int acc = 0;
#pragma unroll 4
    for (int t = 0; t < TT; ++t) {
        acc += ops[t * BB + b];
        pts[t * BB + b] = acc;
    }
}

// level 0 of the stacks = h0/c0 broadcast over batch (normal stores are fine:
// kernel-boundary release flushes L2 to the coherence point before k_main)
__global__ void k_init(const float* __restrict__ h0, const float* __restrict__ c0,
                       float* __restrict__ hS, float* __restrict__ cS) {
    int i = blockIdx.x * 256 + threadIdx.x;   // i = b*HH + h, level 0
    int h = i & (HH - 1);
    hS[i] = h0[h];
    cS[i] = c0[h];
}

__global__ __launch_bounds__(256)
void k_main(const float* __restrict__ x, const int* __restrict__ ops,
            const float* __restrict__ wxi, const float* __restrict__ bi,
            const float* __restrict__ whi, const float* __restrict__ wci,
            const float* __restrict__ wxf, const float* __restrict__ bfp,
            const float* __restrict__ whf, const float* __restrict__ wcf,
            const float* __restrict__ wxc, const float* __restrict__ bcp,
            const float* __restrict__ wxo, const float* __restrict__ bop,
            const float* __restrict__ who, const float* __restrict__ wco,
            float* __restrict__ hS, float* __restrict__ cS,
            const int* __restrict__ pts, unsigned* __restrict__ flags,
            float* __restrict__ out)
{
    const int tid   = threadIdx.x;
    const int blk   = blockIdx.x;
    const int btile = blk >> 4;    // group id: 16 consecutive blocks share a btile
    const int htile = blk & 15;
    const int hl = tid & 15, bl = tid >> 4;
    const int hg = htile * HT + hl;
    const int bg = btile * BT + bl;
    const int wv = tid >> 6;       // wave 0..3
    const int ln = tid & 63;       // lane

    // +4 pad: float4-aligned rows, rows offset by 4 banks (conflict-free b128)
    __shared__ float sh[BT][HH + 4];
    __shared__ float sc[BT][HH + 4];

    const float bi_ = bi[hg], bf_ = bfp[hg], bc_ = bcp[hg], bo_ = bop[hg];
    const float* wxi_r = wxi + hg * INS;
    const float* wxf_r = wxf + hg * INS;
    const float* wxc_r = wxc + hg * INS;
    const float* wxo_r = wxo + hg * INS;
    const float* whi_r = whi + hg * HH;
    const float* whf_r = whf + hg * HH;
    const float* who_r = who + hg * HH;
    const float* wci_r = wci + hg * HH;
    const float* wcf_r = wcf + hg * HH;
    const float* wco_r = wco + hg * HH;

    unsigned* grpflags = flags + btile * 16;

    for (int t = 0; t < TT; ++t) {
        const int tB = t * BB;

        // ---- Phase A: x-projections (no dependence on other blocks) ----
        float xa_i = bi_, xa_f = bf_, xa_c = bc_, xa_o = bo_;
        {
            const float* xrow = x + ((size_t)tB + bg) * INS;
#pragma unroll 8
            for (int k = 0; k < INS; k += 4) {
                float4 xv = *(const float4*)(xrow + k);
                float4 w;
                w = *(const float4*)(wxi_r + k); xa_i += xv.x*w.x + xv.y*w.y + xv.z*w.z + xv.w*w.w;
                w = *(const float4*)(wxf_r + k); xa_f += xv.x*w.x + xv.y*w.y + xv.z*w.z + xv.w*w.w;
                w = *(const float4*)(wxc_r + k); xa_c += xv.x*w.x + xv.y*w.y + xv.z*w.z + xv.w*w.w;
                w = *(const float4*)(wxo_r + k); xa_o += xv.x*w.x + xv.y*w.y + xv.z*w.z + xv.w*w.w;
            }
        }
        const int pt = pts[tB + bg];
        const int op = ops[(t + 1) * BB + bg];

        // ---- Phase B: wait for all 16 group members to finish step t-1 ----
        if (tid < 16) {
            unsigned* f = grpflags + tid;
            const unsigned want = (unsigned)t;
            while (__hip_atomic_load(f, __ATOMIC_RELAXED, __HIP_MEMORY_SCOPE_AGENT) < want)
                __builtin_amdgcn_s_sleep(1);
        }
        __syncthreads();

        // ---- Phase C: gather cur_h/cur_c via coherence point -> LDS ----
#pragma unroll
        for (int r = 0; r < 4; ++r) {
            int row = wv * 4 + r;
            int bgr = btile * BT + row;
            int ptr = pts[tB + bgr];
            size_t base = ((size_t)ptr * BB + bgr) * HH;
#pragma unroll
            for (int i = 0; i < 4; ++i) {
                int col = i * 64 + ln;
                sh[row][col] = ld_coh(hS + base + col);
                sc[row][col] = ld_coh(cS + base + col);
            }
        }
        // prev_h level (pt-1)%129 was last written >= 2 steps ago: safe to
        // prefetch here, overlaps with the compute phase
        float prev = 0.f;
        if (op <= 0) {
            int pm = (pt == 0) ? (SP1 - 1) : (pt - 1);
            prev = ld_coh(hS + ((size_t)pm * BB + bg) * HH + hg);
        }
        __syncthreads();

        // ---- Phase D: 6 dot products over K=256 (weights stay hot in L1/L2) ----
        float a_i = xa_i, a_f = xa_f, a_o = xa_o, a_hf = 0.f;
#pragma unroll 4
        for (int k = 0; k < HH; k += 4) {
            float4 hv = *(const float4*)&sh[bl][k];
            float4 cv = *(const float4*)&sc[bl][k];
            float4 w;
            w = *(const float4*)(whi_r + k); a_i  += hv.x*w.x + hv.y*w.y + hv.z*w.z + hv.w*w.w;
            w = *(const float4*)(wci_r + k); a_i  += cv.x*w.x + cv.y*w.y + cv.z*w.z + cv.w*w.w;
            w = *(const float4*)(whf_r + k); a_hf += hv.x*w.x + hv.y*w.y + hv.z*w.z + hv.w*w.w;
            w = *(const float4*)(wcf_r + k); a_f  += cv.x*w.x + cv.y*w.y + cv.z*w.z + cv.w*w.w;
            w = *(const float4*)(who_r + k); a_o  += hv.x*w.x + hv.y*w.y + hv.z*w.z + hv.w*w.w;
            w = *(const float4*)(wco_r + k); a_o  += cv.x*w.x + cv.y*w.y + cv.z*w.z + cv.w*w.w;
        }

        float ig = sigmoidf_(a_i);
        float fg = sigmoidf_(a_f + a_hf);
        float og = sigmoidf_(a_o);
        float curc = sc[bl][hg];
        float cg = fg * curc + ig * tanhf(xa_c + a_hf);  // NOTE: w_hf reuse, per ref
        float nh = og * tanhf(cg);

        // ---- Phase E: publish via coherence point, then flag ----
        size_t wix = ((size_t)(pt + 1) * BB + bg) * HH + hg;
        st_coh(hS + wix, nh);
        st_coh(cS + wix, cg);
        out[((size_t)tB + bg) * HH + hg] = (op > 0) ? nh : prev;

        asm volatile("s_waitcnt vmcnt(0)" ::: "memory");  // per-wave drain (belt+braces)
        __syncthreads();                                   // drains all waves' vmcnt
        if (tid == 0)
            __hip_atomic_store(grpflags + htile, (unsigned)(t + 1),
                               __ATOMIC_RELAXED, __HIP_MEMORY_SCOPE_AGENT);
    }
}

extern "C" void kernel_launch(void* const* d_in, const int* in_sizes, int n_in,
                              void* d_out, int out_size, void* d_ws, size_t ws_size,
                              hipStream_t stream) {
    const float* x   = (const float*)d_in[0];
    const int*   ops = (const int*)d_in[1];
    const float* wxi = (const float*)d_in[2];
    const float* bi  = (const float*)d_in[3];
    const float* whi = (const float*)d_in[4];
    const float* wci = (const float*)d_in[5];
    const float* wxf = (const float*)d_in[6];
    const float* bf  = (const float*)d_in[7];
    const float* whf = (const float*)d_in[8];
    const float* wcf = (const float*)d_in[9];
    const float* wxc = (const float*)d_in[10];
    const float* bc  = (const float*)d_in[11];
    const float* wxo = (const float*)d_in[12];
    const float* bo  = (const float*)d_in[13];
    const float* who = (const float*)d_in[14];
    const float* wco = (const float*)d_in[15];
    const float* h0  = (const float*)d_in[16];
    const float* c0  = (const float*)d_in[17];
    float* out = (float*)d_out;

    const size_t stackElems = (size_t)SP1 * BB * HH;  // 8,454,144 floats per stack
    float*    hS    = (float*)d_ws;
    float*    cS    = hS + stackElems;
    int*      pts   = (int*)(cS + stackElems);
    unsigned* flags = (unsigned*)(pts + (size_t)TT * BB);
    size_t need = (size_t)((char*)(flags + 256) - (char*)d_ws);
    if (ws_size < need) return;

    // stacks must start as zeros (level 128 IS read as zeros when pt==0)
    hipMemsetAsync(d_ws, 0, stackElems * 2 * sizeof(float), stream);
    hipMemsetAsync((void*)flags, 0, 256 * sizeof(unsigned), stream);
    k_pts<<<1, 256, 0, stream>>>(ops, pts);
    k_init<<<(BB * HH) / 256, 256, 0, stream>>>(h0, c0, hS, cS);
    k_main<<<NBLK, 256, 0, stream>>>(x, ops, wxi, bi, whi, wci, wxf, bf, whf, wcf,
                                     wxc, bc, wxo, bo, who, wco,
                                     hS, cS, pts, flags, out);
}